// Round 4
// baseline (165.577 us; speedup 1.0000x reference)
//
#include <hip/hip_runtime.h>

// Linear attention via bf16 MFMA:
//   KVT[b][v][d] = sum_k V[b,k,v] * (relu(K[b,k,d])+eps)   (fp32 partials over S-chunks)
//   out[b][q,v]  = sum_d (relu(Q[b,q,d])+eps) * KVT[b][v][d]
//
// v5 changes vs v4 (155.9 us; all kernels < 40 us, fills dominate):
//  - kvt: nchunk 16->4, output split 16-way (64v x 64d sub-tiles) -> grid still 512
//    but fp32 partial traffic drops 67 MB -> 16.8 MB (write+read), LDS 64->32 KB.
//    XCD bucket (64 consecutive works) = one full batch b per XCD.
//  - reduce: 4-chunk loop (reads 8.4 MB).
//  - out: vt split 2->4 (stage 64v x 256d = 32 KB) -> grid 1024, higher occupancy;
//    the 4 vt subs of one (qt,b) share the Q tile within an XCD.

#define BB 8
#define SS 4096
#define DD 256
#define DDV 256
#define EPSF 1e-6f

typedef short bf16x8 __attribute__((ext_vector_type(8)));
typedef float f32x4 __attribute__((ext_vector_type(4)));

__device__ __forceinline__ unsigned int f2bf(float f) {
  unsigned int u = __float_as_uint(f);
  u += 0x7FFF + ((u >> 16) & 1);   // RNE
  return u >> 16;
}
__device__ __forceinline__ unsigned int pack2(float a, float b) {
  return f2bf(a) | (f2bf(b) << 16);
}

// Raw barrier that does NOT drain vmcnt: LDS writes are made visible via
// lgkmcnt(0); outstanding global loads (prefetch) stay in flight.
__device__ __forceinline__ void sync_lds() {
  asm volatile("s_waitcnt lgkmcnt(0)" ::: "memory");
  __builtin_amdgcn_s_barrier();
  __builtin_amdgcn_sched_barrier(0);
}

// ---------------- Kernel A: KVT partials ----------------
// grid 16*nchunk*BB, block 512. Per block: 64 v x 64 d, BK=64 pipeline.
__global__ __launch_bounds__(512, 4) void kvt_kernel(
    const float* __restrict__ K, const float* __restrict__ V,
    float* __restrict__ part, int kchunk) {
  const int nchunk  = SS / kchunk;
  const int nblocks = 16 * nchunk * BB;
  // XCD swizzle: block f runs work w = (f%8)*(nblocks/8) + f/8. The 16 subs
  // (vt,dt) of one (chunk,b) are consecutive w -> same XCD; with nchunk=4 one
  // XCD bucket (nblocks/8 = 64 works) is exactly one batch b.
  const int f  = blockIdx.x;
  const int w  = (f & 7) * (nblocks >> 3) + (f >> 3);
  const int sub   = w & 15;
  const int vt    = sub & 3;    // v quarter (64 rows)
  const int dt    = sub >> 2;   // d quarter (64 rows)
  const int rest  = w >> 4;
  const int chunk = rest % nchunk;
  const int b     = rest / nchunk;
  const int k0blk = chunk * kchunk;

  __shared__ ushort Vt[2][64 * 64];  // [v][k] swizzled, 2 x 8 KB
  __shared__ ushort Kt[2][64 * 64];  // [d][k] swizzled, 2 x 8 KB

  const int tid  = threadIdx.x;
  const int lane = tid & 63;
  const int wid  = tid >> 6;   // 0..7
  const int wv   = wid >> 2;   // 0..1 (v dir, 32 rows each)
  const int wd   = wid & 3;    // 0..3 (d dir, 16 rows each)

  f32x4 acc[2];
  acc[0] = (f32x4){0.f, 0.f, 0.f, 0.f};
  acc[1] = (f32x4){0.f, 0.f, 0.f, 0.f};

  const float* Vb = V + (size_t)b * SS * DDV + vt * 64;
  const float* Kb = K + (size_t)b * SS * DD + dt * 64;

  // staging coordinates: 64 rows x 8 octets, 512 threads -> 1 octet each
  const int rs = tid & 63, ob = tid >> 6;   // row, octet 0..7

  float fV[8];
  float fK[8];

  auto issue = [&](int kk) {
    #pragma unroll
    for (int j = 0; j < 8; j++)
      fV[j] = Vb[(size_t)(k0blk + kk + ob * 8 + j) * DDV + rs];
    #pragma unroll
    for (int j = 0; j < 8; j++)
      fK[j] = Kb[(size_t)(k0blk + kk + ob * 8 + j) * DD + rs];
    __builtin_amdgcn_sched_barrier(0);  // pin loads here (prefetch position)
  };

  auto packwrite = [&](int buf) {
    {
      uint4 wq;
      wq.x = pack2(fV[0], fV[1]); wq.y = pack2(fV[2], fV[3]);
      wq.z = pack2(fV[4], fV[5]); wq.w = pack2(fV[6], fV[7]);
      const int co = ob ^ (rs & 7);
      *(uint4*)&Vt[buf][rs * 64 + co * 8] = wq;
    }
    {
      float g[8];
      #pragma unroll
      for (int j = 0; j < 8; j++) g[j] = fmaxf(fK[j], 0.0f) + EPSF;
      uint4 wq;
      wq.x = pack2(g[0], g[1]); wq.y = pack2(g[2], g[3]);
      wq.z = pack2(g[4], g[5]); wq.w = pack2(g[6], g[7]);
      const int co = ob ^ (rs & 7);
      *(uint4*)&Kt[buf][rs * 64 + co * 8] = wq;
    }
  };

  auto mfma_phase = [&](int buf) {
    #pragma unroll
    for (int ks = 0; ks < 2; ks++) {
      const int oct = ks * 4 + (lane >> 4);
      bf16x8 af[2], bfr;
      #pragma unroll
      for (int i = 0; i < 2; i++) {
        const int row = wv * 32 + i * 16 + (lane & 15);
        af[i] = *(const bf16x8*)&Vt[buf][row * 64 + (oct ^ (row & 7)) * 8];
      }
      {
        const int row = wd * 16 + (lane & 15);
        bfr = *(const bf16x8*)&Kt[buf][row * 64 + (oct ^ (row & 7)) * 8];
      }
      #pragma unroll
      for (int i = 0; i < 2; i++)
        acc[i] = __builtin_amdgcn_mfma_f32_16x16x32_bf16(af[i], bfr, acc[i], 0, 0, 0);
    }
  };

  const int nt = kchunk >> 6;
  issue(0);
  packwrite(0);                 // data-dep vmcnt wait inserted by compiler
  if (nt > 1) issue(64);
  sync_lds();

  int cur = 0;
  for (int t = 0; t < nt; t++) {
    mfma_phase(cur);
    if (t + 1 < nt) {
      packwrite(cur ^ 1);       // tile t+1 (loads issued one full iter ago)
      if (t + 2 < nt) issue((t + 2) << 6);
      sync_lds();
    }
    cur ^= 1;
  }

  // epilogue: fp32 partial store, KVT layout [v][d]
  float* pb = part + ((size_t)chunk * BB + b) * (DD * DDV);
  #pragma unroll
  for (int i = 0; i < 2; i++) {
    const int v = vt * 64 + wv * 32 + i * 16 + ((lane >> 4) << 2);
    const int d = dt * 64 + wd * 16 + (lane & 15);
    #pragma unroll
    for (int r = 0; r < 4; r++)
      pb[(size_t)(v + r) * DD + d] = acc[i][r];
  }
}

// ---------------- Kernel R: reduce partials -> bf16 KVT ----------------
// grid 512, block 256; each thread: 4 consecutive d.
__global__ __launch_bounds__(256) void reduce_kernel(
    const float* __restrict__ part, ushort* __restrict__ kvb, int nchunk) {
  const size_t N = (size_t)BB * DD * DDV;        // 524288
  const size_t i4 = ((size_t)blockIdx.x * 256 + threadIdx.x) * 4;
  float4 s = make_float4(0.f, 0.f, 0.f, 0.f);
  for (int c = 0; c < nchunk; c++) {
    float4 p = *(const float4*)&part[(size_t)c * N + i4];
    s.x += p.x; s.y += p.y; s.z += p.z; s.w += p.w;
  }
  uint2 o;
  o.x = pack2(s.x, s.y);
  o.y = pack2(s.z, s.w);
  *(uint2*)&kvb[i4] = o;
}

// ---------------- Kernel B: out = (relu(Q)+eps) @ KVT^T ----------------
// grid 1024 (= 4 vt x 32 qt x 8 b, XCD swizzled), block 512 (8 waves).
// Stage KVT quarter (64v x 256d bf16 = 32 KB) in LDS once, then barrier-free:
// each wave owns 16 q rows; 8 unrolled dc steps of {prefetched global Q loads,
// 4 swizzled ds_read_b128, 4 MFMA}.
__global__ __launch_bounds__(512, 4) void out_kernel(
    const float* __restrict__ Q, const ushort* __restrict__ kvb,
    float* __restrict__ out) {
  // XCD swizzle: the 4 vt subs of one (qt,b) are consecutive w -> same XCD,
  // so the shared Q tile is HBM-fetched once. Bucket (128 works) = one b.
  const int f  = blockIdx.x;
  const int w  = (f & 7) * 128 + (f >> 3);   // nblocks = 1024
  const int vt   = w & 3;
  const int rest = w >> 2;     // 0..255
  const int qt   = rest & 31;
  const int b    = rest >> 5;
  const int q0   = qt * 128;

  __shared__ ushort KVs[64 * 256];  // [v-local][d], 16B-chunk XOR swizzle, 32 KB

  const int tid  = threadIdx.x;
  const int lane = tid & 63;
  const int wq   = tid >> 6;           // wave 0..7 -> q sub-tile (16 rows)
  const int lq   = lane & 15;
  const int lk   = (lane >> 4) << 3;   // 0,8,16,24

  const float* Qw = Q + ((size_t)b * SS + q0 + wq * 16) * DD;

  // prefetch first Q fragment (raw) before staging; sync_lds won't drain it
  float4 x0 = *(const float4*)&Qw[(size_t)lq * DD + lk];
  float4 y0 = *(const float4*)&Qw[(size_t)lq * DD + lk + 4];

  // ---- stage KVT quarter into LDS (coalesced 16B chunks, swizzled dest) ----
  {
    const ushort* src = kvb + (size_t)b * DD * DDV + (size_t)vt * 64 * DD;
    #pragma unroll
    for (int p = 0; p < 4; p++) {
      const int chunk = p * 512 + tid;     // 2048 chunks of 16B
      const int row = chunk >> 5;          // 0..63 (v-local)
      const int c   = chunk & 31;          // 16B chunk within row
      uint4 val = *(const uint4*)&src[row * DD + c * 8];
      const int cs = c ^ (row & 7);
      *(uint4*)&KVs[row * DD + cs * 8] = val;
    }
  }

  f32x4 acc[4];
  #pragma unroll
  for (int j = 0; j < 4; j++) acc[j] = (f32x4){0.f, 0.f, 0.f, 0.f};

  sync_lds();

  #pragma unroll
  for (int s = 0; s < 8; s++) {
    float4 xn, yn;
    if (s < 7) {
      const float* p = &Qw[(size_t)lq * DD + (s + 1) * 32 + lk];
      xn = *(const float4*)p;
      yn = *(const float4*)(p + 4);
    }
    uint4 u;
    u.x = pack2(fmaxf(x0.x, 0.f) + EPSF, fmaxf(x0.y, 0.f) + EPSF);
    u.y = pack2(fmaxf(x0.z, 0.f) + EPSF, fmaxf(x0.w, 0.f) + EPSF);
    u.z = pack2(fmaxf(y0.x, 0.f) + EPSF, fmaxf(y0.y, 0.f) + EPSF);
    u.w = pack2(fmaxf(y0.z, 0.f) + EPSF, fmaxf(y0.w, 0.f) + EPSF);
    const bf16x8 af = *(bf16x8*)&u;

    bf16x8 bfr[4];
    const int oct = s * 4 + (lane >> 4);
    #pragma unroll
    for (int j = 0; j < 4; j++) {
      const int row = j * 16 + lq;
      bfr[j] = *(const bf16x8*)&KVs[row * DD + ((oct ^ (row & 7)) << 3)];
    }
    #pragma unroll
    for (int j = 0; j < 4; j++)
      acc[j] = __builtin_amdgcn_mfma_f32_16x16x32_bf16(af, bfr[j], acc[j], 0, 0, 0);

    x0 = xn; y0 = yn;
  }

  float* ob = out + ((size_t)b * SS + q0 + wq * 16) * DDV;
  const int qr = (lane >> 4) << 2;
  #pragma unroll
  for (int j = 0; j < 4; j++) {
    const int v = vt * 64 + j * 16 + lq;
    #pragma unroll
    for (int r = 0; r < 4; r++)
      ob[(size_t)(qr + r) * DDV + v] = acc[j][r];
  }
}

extern "C" void kernel_launch(void* const* d_in, const int* in_sizes, int n_in,
                              void* d_out, int out_size, void* d_ws, size_t ws_size,
                              hipStream_t stream) {
  const float* Q = (const float*)d_in[0];
  const float* K = (const float*)d_in[1];
  const float* V = (const float*)d_in[2];
  float* out = (float*)d_out;

  const size_t N = (size_t)BB * DD * DDV;  // 524288 elements
  // ws: [nchunk fp32 partials][bf16 KVT]
  int nchunk = 4;
  while (nchunk > 1 && (size_t)nchunk * N * 4 + N * 2 > ws_size) nchunk >>= 1;
  const int kchunk = SS / nchunk;

  float* part = (float*)d_ws;
  ushort* kvb = (ushort*)(part + (size_t)nchunk * N);

  const int nblocks = 16 * nchunk * BB;
  kvt_kernel<<<dim3(nblocks), 512, 0, stream>>>(K, V, part, kchunk);
  reduce_kernel<<<dim3(512), 256, 0, stream>>>(part, kvb, nchunk);
  out_kernel<<<dim3(1024), 512, 0, stream>>>(Q, kvb, out);
}

// Round 5
// 164.782 us; speedup vs baseline: 1.0048x; 1.0048x over previous
//
#include <hip/hip_runtime.h>

// Linear attention via bf16 MFMA:
//   KVT[b][v][d] = sum_k V[b,k,v] * (relu(K[b,k,d])+eps)   (fp32 partials over S-chunks)
//   out[b][q,v]  = sum_d (relu(Q[b,q,d])+eps) * KVT[b][v][d]
//
// v6 changes vs v5 (165.6 us; v5's 64x64 kvt tiles doubled staging redundancy and
// halved MFMA density -> regression vs v4's 155.9):
//  - kvt: nchunk=8, 8 sub-tiles of 128v x 64d -> grid stays 512 (full device BW),
//    per-thread density back to 8 MFMA / 24 loads, LDS 48 KB (2 blocks/CU),
//    fp32 partial round-trip 64 MB (v4) -> 32 MB.
//  - reduce: 8-chunk loop.
//  - out: unchanged from v5 (proven < 40 us).

#define BB 8
#define SS 4096
#define DD 256
#define DDV 256
#define EPSF 1e-6f

typedef short bf16x8 __attribute__((ext_vector_type(8)));
typedef float f32x4 __attribute__((ext_vector_type(4)));

__device__ __forceinline__ unsigned int f2bf(float f) {
  unsigned int u = __float_as_uint(f);
  u += 0x7FFF + ((u >> 16) & 1);   // RNE
  return u >> 16;
}
__device__ __forceinline__ unsigned int pack2(float a, float b) {
  return f2bf(a) | (f2bf(b) << 16);
}

// Raw barrier that does NOT drain vmcnt: LDS writes are made visible via
// lgkmcnt(0); outstanding global loads (prefetch) stay in flight.
__device__ __forceinline__ void sync_lds() {
  asm volatile("s_waitcnt lgkmcnt(0)" ::: "memory");
  __builtin_amdgcn_s_barrier();
  __builtin_amdgcn_sched_barrier(0);
}

// ---------------- Kernel A: KVT partials ----------------
// grid 8*nchunk*BB = 512, block 512. Per block: 128 v x 64 d, BK=64 pipeline.
__global__ __launch_bounds__(512, 4) void kvt_kernel(
    const float* __restrict__ K, const float* __restrict__ V,
    float* __restrict__ part, int kchunk) {
  const int nchunk  = SS / kchunk;
  const int nblocks = 8 * nchunk * BB;
  // XCD swizzle: block f runs work w = (f%8)*(nblocks/8) + f/8. The 8 subs
  // (vt,dt) of one (chunk,b) are consecutive w -> same XCD and temporally
  // adjacent, so the K/V slabs are HBM-fetched once and L2-reused.
  const int f  = blockIdx.x;
  const int w  = (f & 7) * (nblocks >> 3) + (f >> 3);
  const int sub   = w & 7;
  const int vt    = sub & 1;    // v half (128 rows)
  const int dt    = sub >> 1;   // d quarter (64 rows)
  const int rest  = w >> 3;
  const int chunk = rest % nchunk;
  const int b     = rest / nchunk;
  const int k0blk = chunk * kchunk;

  __shared__ ushort Vt[2][128 * 64];  // [v][k] swizzled, 2 x 16 KB
  __shared__ ushort Kt[2][64 * 64];   // [d][k] swizzled, 2 x 8 KB

  const int tid  = threadIdx.x;
  const int lane = tid & 63;
  const int wid  = tid >> 6;   // 0..7
  const int wv   = wid >> 2;   // 0..1 (v dir, 64 rows each)
  const int wd   = wid & 3;    // 0..3 (d dir, 16 rows each)
  const int lq   = lane & 15;

  f32x4 acc[4];
  #pragma unroll
  for (int i = 0; i < 4; i++) acc[i] = (f32x4){0.f, 0.f, 0.f, 0.f};

  const float* Vb = V + (size_t)b * SS * DDV + vt * 128;
  const float* Kb = K + (size_t)b * SS * DD + dt * 64;

  // staging coordinates (fixed per thread):
  //   V: 128 rows x 8 octets = 1024 tasks -> 2 per thread
  //   K:  64 rows x 8 octets =  512 tasks -> 1 per thread
  const int rv = tid & 127, obv = tid >> 7;  // 0..3, p adds 4
  const int rk = tid & 63,  obk = tid >> 6;  // 0..7

  float fV[2][8];
  float fK[8];

  auto issue = [&](int kk) {
    #pragma unroll
    for (int p = 0; p < 2; p++) {
      const int o = obv + p * 4;
      #pragma unroll
      for (int j = 0; j < 8; j++)
        fV[p][j] = Vb[(size_t)(k0blk + kk + o * 8 + j) * DDV + rv];
    }
    #pragma unroll
    for (int j = 0; j < 8; j++)
      fK[j] = Kb[(size_t)(k0blk + kk + obk * 8 + j) * DD + rk];
    __builtin_amdgcn_sched_barrier(0);  // pin loads here (prefetch position)
  };

  auto packwrite = [&](int buf) {
    #pragma unroll
    for (int p = 0; p < 2; p++) {
      const int o = obv + p * 4;
      uint4 wq;
      wq.x = pack2(fV[p][0], fV[p][1]); wq.y = pack2(fV[p][2], fV[p][3]);
      wq.z = pack2(fV[p][4], fV[p][5]); wq.w = pack2(fV[p][6], fV[p][7]);
      const int co = o ^ (rv & 7);
      *(uint4*)&Vt[buf][rv * 64 + co * 8] = wq;
    }
    {
      float g[8];
      #pragma unroll
      for (int j = 0; j < 8; j++) g[j] = fmaxf(fK[j], 0.0f) + EPSF;
      uint4 wq;
      wq.x = pack2(g[0], g[1]); wq.y = pack2(g[2], g[3]);
      wq.z = pack2(g[4], g[5]); wq.w = pack2(g[6], g[7]);
      const int co = obk ^ (rk & 7);
      *(uint4*)&Kt[buf][rk * 64 + co * 8] = wq;
    }
  };

  auto mfma_phase = [&](int buf) {
    #pragma unroll
    for (int ks = 0; ks < 2; ks++) {
      const int oct = ks * 4 + (lane >> 4);
      bf16x8 af[4], bfr;
      #pragma unroll
      for (int i = 0; i < 4; i++) {
        const int row = wv * 64 + i * 16 + lq;
        af[i] = *(const bf16x8*)&Vt[buf][row * 64 + (oct ^ (row & 7)) * 8];
      }
      {
        const int row = wd * 16 + lq;
        bfr = *(const bf16x8*)&Kt[buf][row * 64 + (oct ^ (row & 7)) * 8];
      }
      #pragma unroll
      for (int i = 0; i < 4; i++)
        acc[i] = __builtin_amdgcn_mfma_f32_16x16x32_bf16(af[i], bfr, acc[i], 0, 0, 0);
    }
  };

  const int nt = kchunk >> 6;
  issue(0);
  packwrite(0);                 // data-dep vmcnt wait inserted by compiler
  if (nt > 1) issue(64);
  sync_lds();

  int cur = 0;
  for (int t = 0; t < nt; t++) {
    mfma_phase(cur);
    if (t + 1 < nt) {
      packwrite(cur ^ 1);       // tile t+1 (loads issued one full iter ago)
      if (t + 2 < nt) issue((t + 2) << 6);
      sync_lds();
    }
    cur ^= 1;
  }

  // epilogue: fp32 partial store, KVT layout [v][d]
  float* pb = part + ((size_t)chunk * BB + b) * (DD * DDV);
  #pragma unroll
  for (int i = 0; i < 4; i++) {
    const int v = vt * 128 + wv * 64 + i * 16 + ((lane >> 4) << 2);
    const int d = dt * 64 + wd * 16 + lq;
    #pragma unroll
    for (int r = 0; r < 4; r++)
      pb[(size_t)(v + r) * DD + d] = acc[i][r];
  }
}

// ---------------- Kernel R: reduce partials -> bf16 KVT ----------------
// grid 512, block 256; each thread: 4 consecutive d.
__global__ __launch_bounds__(256) void reduce_kernel(
    const float* __restrict__ part, ushort* __restrict__ kvb, int nchunk) {
  const size_t N = (size_t)BB * DD * DDV;        // 524288
  const size_t i4 = ((size_t)blockIdx.x * 256 + threadIdx.x) * 4;
  float4 s = make_float4(0.f, 0.f, 0.f, 0.f);
  for (int c = 0; c < nchunk; c++) {
    float4 p = *(const float4*)&part[(size_t)c * N + i4];
    s.x += p.x; s.y += p.y; s.z += p.z; s.w += p.w;
  }
  uint2 o;
  o.x = pack2(s.x, s.y);
  o.y = pack2(s.z, s.w);
  *(uint2*)&kvb[i4] = o;
}

// ---------------- Kernel B: out = (relu(Q)+eps) @ KVT^T ----------------
// grid 1024 (= 4 vt x 32 qt x 8 b, XCD swizzled), block 512 (8 waves).
// Stage KVT quarter (64v x 256d bf16 = 32 KB) in LDS once, then barrier-free:
// each wave owns 16 q rows; 8 unrolled dc steps of {prefetched global Q loads,
// 4 swizzled ds_read_b128, 4 MFMA}.
__global__ __launch_bounds__(512, 4) void out_kernel(
    const float* __restrict__ Q, const ushort* __restrict__ kvb,
    float* __restrict__ out) {
  // XCD swizzle: the 4 vt subs of one (qt,b) are consecutive w -> same XCD,
  // so the shared Q tile is HBM-fetched once. Bucket (128 works) = one b.
  const int f  = blockIdx.x;
  const int w  = (f & 7) * 128 + (f >> 3);   // nblocks = 1024
  const int vt   = w & 3;
  const int rest = w >> 2;     // 0..255
  const int qt   = rest & 31;
  const int b    = rest >> 5;
  const int q0   = qt * 128;

  __shared__ ushort KVs[64 * 256];  // [v-local][d], 16B-chunk XOR swizzle, 32 KB

  const int tid  = threadIdx.x;
  const int lane = tid & 63;
  const int wq   = tid >> 6;           // wave 0..7 -> q sub-tile (16 rows)
  const int lq   = lane & 15;
  const int lk   = (lane >> 4) << 3;   // 0,8,16,24

  const float* Qw = Q + ((size_t)b * SS + q0 + wq * 16) * DD;

  // prefetch first Q fragment (raw) before staging; sync_lds won't drain it
  float4 x0 = *(const float4*)&Qw[(size_t)lq * DD + lk];
  float4 y0 = *(const float4*)&Qw[(size_t)lq * DD + lk + 4];

  // ---- stage KVT quarter into LDS (coalesced 16B chunks, swizzled dest) ----
  {
    const ushort* src = kvb + (size_t)b * DD * DDV + (size_t)vt * 64 * DD;
    #pragma unroll
    for (int p = 0; p < 4; p++) {
      const int chunk = p * 512 + tid;     // 2048 chunks of 16B
      const int row = chunk >> 5;          // 0..63 (v-local)
      const int c   = chunk & 31;          // 16B chunk within row
      uint4 val = *(const uint4*)&src[row * DD + c * 8];
      const int cs = c ^ (row & 7);
      *(uint4*)&KVs[row * DD + cs * 8] = val;
    }
  }

  f32x4 acc[4];
  #pragma unroll
  for (int j = 0; j < 4; j++) acc[j] = (f32x4){0.f, 0.f, 0.f, 0.f};

  sync_lds();

  #pragma unroll
  for (int s = 0; s < 8; s++) {
    float4 xn, yn;
    if (s < 7) {
      const float* p = &Qw[(size_t)lq * DD + (s + 1) * 32 + lk];
      xn = *(const float4*)p;
      yn = *(const float4*)(p + 4);
    }
    uint4 u;
    u.x = pack2(fmaxf(x0.x, 0.f) + EPSF, fmaxf(x0.y, 0.f) + EPSF);
    u.y = pack2(fmaxf(x0.z, 0.f) + EPSF, fmaxf(x0.w, 0.f) + EPSF);
    u.z = pack2(fmaxf(y0.x, 0.f) + EPSF, fmaxf(y0.y, 0.f) + EPSF);
    u.w = pack2(fmaxf(y0.z, 0.f) + EPSF, fmaxf(y0.w, 0.f) + EPSF);
    const bf16x8 af = *(bf16x8*)&u;

    bf16x8 bfr[4];
    const int oct = s * 4 + (lane >> 4);
    #pragma unroll
    for (int j = 0; j < 4; j++) {
      const int row = j * 16 + lq;
      bfr[j] = *(const bf16x8*)&KVs[row * DD + ((oct ^ (row & 7)) << 3)];
    }
    #pragma unroll
    for (int j = 0; j < 4; j++)
      acc[j] = __builtin_amdgcn_mfma_f32_16x16x32_bf16(af, bfr[j], acc[j], 0, 0, 0);

    x0 = xn; y0 = yn;
  }

  float* ob = out + ((size_t)b * SS + q0 + wq * 16) * DDV;
  const int qr = (lane >> 4) << 2;
  #pragma unroll
  for (int j = 0; j < 4; j++) {
    const int v = vt * 64 + j * 16 + lq;
    #pragma unroll
    for (int r = 0; r < 4; r++)
      ob[(size_t)(qr + r) * DDV + v] = acc[j][r];
  }
}

extern "C" void kernel_launch(void* const* d_in, const int* in_sizes, int n_in,
                              void* d_out, int out_size, void* d_ws, size_t ws_size,
                              hipStream_t stream) {
  const float* Q = (const float*)d_in[0];
  const float* K = (const float*)d_in[1];
  const float* V = (const float*)d_in[2];
  float* out = (float*)d_out;

  const size_t N = (size_t)BB * DD * DDV;  // 524288 elements
  // ws: [nchunk fp32 partials][bf16 KVT]
  int nchunk = 8;
  while (nchunk > 1 && (size_t)nchunk * N * 4 + N * 2 > ws_size) nchunk >>= 1;
  const int kchunk = SS / nchunk;

  float* part = (float*)d_ws;
  ushort* kvb = (ushort*)(part + (size_t)nchunk * N);

  const int nblocks = 8 * nchunk * BB;
  kvt_kernel<<<dim3(nblocks), 512, 0, stream>>>(K, V, part, kchunk);
  reduce_kernel<<<dim3(512), 256, 0, stream>>>(part, kvb, nchunk);
  out_kernel<<<dim3(1024), 512, 0, stream>>>(Q, kvb, out);
}